// Round 2
// baseline (291.104 us; speedup 1.0000x reference)
//
#include <hip/hip_runtime.h>

#define BS    64
#define CIN   128
#define OCH   128
#define HW    56
#define KEXP  8
#define KTOT  1152             // 9 * 128
#define NSTEP 36               // k-steps of 32
#define CELLE 40               // elems per cell: 32 ch + 8 pad = 80 B
#define ROWE  (58 * CELLE)     // 2320 elems per padded row
#define PLANEE (58 * ROWE)     // 134560 elems per (b,q) plane
#define WMIX_PS (NSTEP * OCH * 32)   // 147456 elems per sample
#define SLAB_CHUNKS 1160       // real 16B chunks per staged quarter (4 rows)
#define BUFE (SLAB_CHUNKS * 8) // 9280 ushorts = 18,560 B per buffer
#define XT_BLOCKS (BS * 58)    // 3712

typedef __bf16 bf16x8 __attribute__((ext_vector_type(8)));
typedef float  f32x4  __attribute__((ext_vector_type(4)));

__device__ __forceinline__ unsigned f2bf(float f) {
    union { float f; unsigned u; } v; v.f = f;
    unsigned r = v.u + 0x7fffu + ((v.u >> 16) & 1u);   // RNE
    return r >> 16;
}

__device__ __forceinline__ void gl16(const unsigned short* g, unsigned short* l) {
    __builtin_amdgcn_global_load_lds(
        (const __attribute__((address_space(1))) void*)g,
        (__attribute__((address_space(3))) void*)l, 16, 0, 0);
}

// Fused prep: blocks [0, 3712) build x_t by DIRECT GATHER (no LDS transpose,
// coalesced 16B stores); blocks [3712, 4224) build wmix. Running both in one
// dispatch overlaps them and removes a launch gap.
__global__ __launch_bounds__(256) void prep_fused(
        const float* __restrict__ x, const float* __restrict__ rw,
        const float* __restrict__ wgt,
        unsigned short* __restrict__ xt, unsigned short* __restrict__ wmix) {
    __shared__ float wlds[KEXP * KTOT];     // 36.9 KB (wmix part only)
    __shared__ float rwl[16 * KEXP];
    int blk = blockIdx.x;
    int tid = threadIdx.x;

    if (blk < XT_BLOCKS) {
        // x [64][128][56][56] f32 -> x_t [64][4][58][58][40] bf16 (zero halos,
        // cell = 32 channels + 8 pad). Thread -> (q, cell, p) chunk of 16 B.
        int b = blk / 58, ihp = blk - b * 58;
        bool border = (ihp == 0) || (ihp == 57);
        const float* xb = x + (size_t)b * CIN * HW * HW + (size_t)(ihp - 1) * HW;
        for (int j = tid; j < 4 * 58 * 5; j += 256) {          // 1160 chunks
            int q = j / 290, rr = j - q * 290;
            int cell = rr / 5, p = rr - cell * 5;
            union { unsigned short u[8]; uint4 v; } o;
            o.v = make_uint4(0u, 0u, 0u, 0u);
            if (!border && p < 4 && cell >= 1 && cell <= 56) {
                const float* src = xb + (size_t)(q * 32 + p * 8) * (HW * HW) + (cell - 1);
                #pragma unroll
                for (int k = 0; k < 8; ++k)
                    o.u[k] = (unsigned short)f2bf(src[(size_t)k * (HW * HW)]);
            }
            *(uint4*)&xt[((size_t)(b * 4 + q)) * PLANEE + (size_t)ihp * ROWE
                         + cell * CELLE + p * 8] = o.v;
        }
    } else {
        // wmix layout: [b][s=0..35][oc][32] bf16, s = q*9 + rs.
        int wb = blk - XT_BLOCKS;
        int oc = wb & 127, bg = wb >> 7;
        if (tid < 16 * KEXP) rwl[tid] = rw[bg * 16 * KEXP + tid];
        const float* wsrc = wgt + (size_t)oc * KTOT;
        #pragma unroll
        for (int e = 0; e < KEXP; ++e) {
            const float* we = wsrc + (size_t)e * OCH * KTOT;
            for (int j = tid; j < KTOT; j += 256) wlds[e * KTOT + j] = we[j];
        }
        __syncthreads();
        for (int t = tid; t < KTOT; t += 256) {
            int c = t & 127, rs = t >> 7;
            int q = c >> 5, cl = c & 31;
            size_t oidx = ((size_t)(q * 9 + rs) * OCH + oc) * 32 + cl;
            float w8[KEXP];
            #pragma unroll
            for (int e = 0; e < KEXP; ++e) w8[e] = wlds[e * KTOT + c * 9 + rs];
            #pragma unroll
            for (int b = 0; b < 16; ++b) {
                float a = 0.f;
                #pragma unroll
                for (int e = 0; e < KEXP; ++e) a += rwl[b * KEXP + e] * w8[e];
                wmix[(size_t)(bg * 16 + b) * WMIX_PS + oidx] = (unsigned short)f2bf(a);
            }
        }
    }
}

// Block = (sample b = blk&63, 2-row tile). M=128 x N=112, 4 waves (32 oc each).
// K in 4 quarters (32 ch x 9 k-steps). Quarter slab (1160 x 16 B) staged with
// global_load_lds into an 18,560 B double buffer (37,120 B total -> 4 blocks/CU,
// 16 waves). stage(q+1) issues at top of compute(q). A streams from XCD-local L2
// with a depth-2 register pipeline. Bias computed inline in the epilogue.
__global__ __launch_bounds__(256, 4) void condconv_mfma(
        const unsigned short* __restrict__ xt, const unsigned short* __restrict__ wmix,
        const float* __restrict__ rw, const float* __restrict__ bias,
        float* __restrict__ out) {
    __shared__ unsigned short patch[2][BUFE];   // 37,120 B

    int blk  = blockIdx.x;
    int b    = blk & 63;
    int tile = blk >> 6;               // 0..27
    int oh0  = tile * 2;
    int tid  = threadIdx.x;
    int wave = tid >> 6, lane = tid & 63, ln = lane & 15, quad = lane >> 4;

    // A: wmix[b][s][oc][32]; per-lane base for (oc = wave*32+ln, k-sub = quad*8)
    const unsigned short* ap = wmix + (size_t)b * WMIX_PS
                             + (size_t)(wave * 32 + ln) * 32 + quad * 8;

    const unsigned short* xbase = xt + (size_t)(b * 4) * PLANEE + (size_t)oh0 * ROWE;

    // B bases + output offsets: n = nt*16 + ln
    int cb[7], offn[7];
    #pragma unroll
    for (int nt = 0; nt < 7; ++nt) {
        int n   = nt * 16 + ln;
        int row = (n >= 56) ? 1 : 0;
        int ow  = n - row * 56;
        cb[nt]   = (row * 58 + ow) * CELLE + quad * 8;
        offn[nt] = (oh0 + row) * HW + ow;
    }

    f32x4 acc[2][7] = {};

    auto stage = [&](int q, int bf) {
        const unsigned short* sq = xbase + (size_t)q * PLANEE;
        #pragma unroll
        for (int it = 0; it < 5; ++it) {
            int ci = it * 256 + tid;                   // chunk index, linear in lane
            if (ci < SLAB_CHUNKS)
                gl16(sq + (size_t)ci * 8, &patch[bf][0] + (size_t)ci * 8);
        }
    };

    stage(0, 0);
    bf16x8 pa0[2], pa1[2];
    pa0[0] = *(const bf16x8*)(ap);
    pa1[0] = *(const bf16x8*)(ap + 512);
    pa0[1] = *(const bf16x8*)(ap + 4096);
    pa1[1] = *(const bf16x8*)(ap + 4096 + 512);
    __syncthreads();

    #pragma unroll
    for (int q = 0; q < 4; ++q) {
        if (q < 3) stage(q + 1, (q + 1) & 1);
        #pragma unroll
        for (int s9 = 0; s9 < 9; ++s9) {
            const int s = q * 9 + s9;
            bf16x8 ca0 = pa0[s & 1], ca1 = pa1[s & 1];
            const int sp = (s + 2 < NSTEP) ? (s + 2) : (NSTEP - 1);
            pa0[s & 1] = *(const bf16x8*)(ap + (size_t)sp * 4096);
            pa1[s & 1] = *(const bf16x8*)(ap + (size_t)sp * 4096 + 512);
            const int r = s9 / 3, sc = s9 - r * 3;
            const int pshift = (r * 58 + sc) * CELLE;
            #pragma unroll
            for (int nt = 0; nt < 7; ++nt) {
                bf16x8 bb = *(const bf16x8*)&patch[q & 1][cb[nt] + pshift];
                acc[0][nt] = __builtin_amdgcn_mfma_f32_16x16x32_bf16(ca0, bb, acc[0][nt], 0, 0, 0);
                acc[1][nt] = __builtin_amdgcn_mfma_f32_16x16x32_bf16(ca1, bb, acc[1][nt], 0, 0, 0);
            }
        }
        __syncthreads();
    }

    // epilogue: D layout col(lane&15)=pixel, row(quad*4+reg)=oc; bias inline
    float rwr[KEXP];
    #pragma unroll
    for (int e = 0; e < KEXP; ++e) rwr[e] = rw[b * KEXP + e];
    float* ob = out + (size_t)b * OCH * HW * HW;
    #pragma unroll
    for (int mt = 0; mt < 2; ++mt) {
        #pragma unroll
        for (int rg = 0; rg < 4; ++rg) {
            int oc = wave * 32 + mt * 16 + quad * 4 + rg;
            float bv = 0.f;
            #pragma unroll
            for (int e = 0; e < KEXP; ++e) bv += rwr[e] * bias[e * OCH + oc];
            #pragma unroll
            for (int nt = 0; nt < 7; ++nt)
                ob[(size_t)oc * (HW * HW) + offn[nt]] = acc[mt][nt][rg] + bv;
        }
    }
}

extern "C" void kernel_launch(void* const* d_in, const int* in_sizes, int n_in,
                              void* d_out, int out_size, void* d_ws, size_t ws_size,
                              hipStream_t stream) {
    (void)in_sizes; (void)n_in; (void)out_size; (void)ws_size;
    const float* x    = (const float*)d_in[0];
    const float* rw   = (const float*)d_in[1];
    const float* wgt  = (const float*)d_in[2];
    const float* bias = (const float*)d_in[3];
    float* outp = (float*)d_out;

    // ws layout: wmix (18,874,368 B) | x_t (68,894,720 B)
    unsigned short* wmix = (unsigned short*)d_ws;
    unsigned short* xtw  = (unsigned short*)((char*)d_ws + (size_t)BS * WMIX_PS * 2);

    hipLaunchKernelGGL(prep_fused, dim3(XT_BLOCKS + OCH * 4), dim3(256), 0, stream,
                       x, rw, wgt, xtw, wmix);
    hipLaunchKernelGGL(condconv_mfma, dim3(BS * 28), dim3(256), 0, stream,
                       xtw, wmix, rw, bias, outp);
}

// Round 3
// 271.289 us; speedup vs baseline: 1.0730x; 1.0730x over previous
//
#include <hip/hip_runtime.h>

#define BS    64
#define CIN   128
#define OCH   128
#define HW    56
#define KEXP  8
#define KTOT  1152             // 9 * 128
#define NSTEP 36               // k-steps of 32
#define CELLE 40               // elems per cell: 32 ch + 8 pad = 80 B
#define ROWE  (58 * CELLE)     // 2320 elems per padded row
#define PLANEE (58 * ROWE)     // 134560 elems per (b,q) plane
#define WMIX_PS (NSTEP * OCH * 32)   // 147456 elems per sample
#define SLAB_CHUNKS 1160       // real 16B chunks per staged quarter (4 rows)
#define BUFE 10240             // 1280 chunks (incl. clamp pad) = 20,480 B per buffer
#define TPAD 58                // LDS row stride (words Δ per 8-ch step ≡ 8 mod 32 -> conflict-free)

typedef __bf16 bf16x8 __attribute__((ext_vector_type(8)));
typedef float  f32x4  __attribute__((ext_vector_type(4)));

__device__ __forceinline__ unsigned f2bf(float f) {
    union { float f; unsigned u; } v; v.f = f;
    unsigned r = v.u + 0x7fffu + ((v.u >> 16) & 1u);   // RNE
    return r >> 16;
}

__device__ __forceinline__ void gl16(const unsigned short* g, unsigned short* l) {
    __builtin_amdgcn_global_load_lds(
        (const __attribute__((address_space(1))) void*)g,
        (__attribute__((address_space(3))) void*)l, 16, 0, 0);
}

// x [64][128][56][56] f32 -> x_t [64][4][58][58][40] bf16 (zero halos,
// cell = 32 channels + 8 pad). Block = (b, padded row ihp).
// Phase 1: float4 loads, bf16 pack into LDS [c][TPAD=58].
// Phase 2: 8-channel gather per 16B chunk, conflict-free (stride-58 rows),
// fully-coalesced uint4 stores.
__global__ __launch_bounds__(256) void prep_xt(const float* __restrict__ x,
                                               unsigned short* __restrict__ xt) {
    __shared__ unsigned short t[CIN * TPAD];   // 14,848 B
    int b = blockIdx.x, ihp = blockIdx.y;      // ihp in [0,58)
    int tid = threadIdx.x;
    bool border = (ihp == 0) || (ihp == 57);
    if (!border) {
        int ih = ihp - 1;
        const float* xr = x + (size_t)b * CIN * HW * HW + (size_t)ih * HW;
        #pragma unroll
        for (int i7 = 0; i7 < 7; ++i7) {               // 1792 float4 = 7/thread
            int i = i7 * 256 + tid;
            int c = i / 14, w4 = i - c * 14;
            float4 v = *(const float4*)(xr + (size_t)c * (HW * HW) + w4 * 4);
            unsigned lo = f2bf(v.x) | (f2bf(v.y) << 16);
            unsigned hi = f2bf(v.z) | (f2bf(v.w) << 16);
            *(unsigned*)&t[c * TPAD + w4 * 4]     = lo;
            *(unsigned*)&t[c * TPAD + w4 * 4 + 2] = hi;
        }
    }
    __syncthreads();
    for (int j = tid; j < 4 * 58 * 5; j += 256) {      // 1160 chunks
        int q = j / 290, rr = j - q * 290;
        int cell = rr / 5, p = rr - cell * 5;
        union { unsigned short u[8]; uint4 v; } o;
        o.v = make_uint4(0u, 0u, 0u, 0u);
        if (!border && p < 4 && cell >= 1 && cell <= 56) {
            #pragma unroll
            for (int k = 0; k < 8; ++k)
                o.u[k] = t[(q * 32 + p * 8 + k) * TPAD + (cell - 1)];
        }
        *(uint4*)&xt[((size_t)(b * 4 + q)) * PLANEE + (size_t)ihp * ROWE
                     + cell * CELLE + p * 8] = o.v;
    }
}

// Block = (oc, b-group of 16). wmix layout: [b][s=0..35][oc][32] bf16,
// s = q*9 + rs, chunk = channels q*32..q*32+31 of tap rs.
__global__ __launch_bounds__(256) void prep_wmix(
        const float* __restrict__ rw, const float* __restrict__ wgt,
        unsigned short* __restrict__ wmix) {
    __shared__ float wlds[KEXP * KTOT];     // 36.9 KB
    __shared__ float rwl[16 * KEXP];
    int oc  = blockIdx.x;
    int bg  = blockIdx.y;
    int tid = threadIdx.x;

    if (tid < 16 * KEXP) rwl[tid] = rw[bg * 16 * KEXP + tid];
    const float* wsrc = wgt + (size_t)oc * KTOT;
    #pragma unroll
    for (int e = 0; e < KEXP; ++e) {
        const float* we = wsrc + (size_t)e * OCH * KTOT;
        for (int j = tid; j < KTOT; j += 256) wlds[e * KTOT + j] = we[j];
    }
    __syncthreads();

    for (int t = tid; t < KTOT; t += 256) {
        int c = t & 127, rs = t >> 7;
        int q = c >> 5, cl = c & 31;
        size_t oidx = ((size_t)(q * 9 + rs) * OCH + oc) * 32 + cl;
        float w8[KEXP];
        #pragma unroll
        for (int e = 0; e < KEXP; ++e) w8[e] = wlds[e * KTOT + c * 9 + rs];
        #pragma unroll
        for (int b = 0; b < 16; ++b) {
            float a = 0.f;
            #pragma unroll
            for (int e = 0; e < KEXP; ++e) a += rwl[b * KEXP + e] * w8[e];
            wmix[(size_t)(bg * 16 + b) * WMIX_PS + oidx] = (unsigned short)f2bf(a);
        }
    }
}

__global__ __launch_bounds__(256) void prep_bmix(
        const float* __restrict__ rw, const float* __restrict__ bias,
        float* __restrict__ bmix) {
    int i = blockIdx.x * 256 + threadIdx.x;
    int b = i >> 7, oc = i & 127;
    float a = 0.f;
    #pragma unroll
    for (int e = 0; e < KEXP; ++e) a += rw[b * KEXP + e] * bias[e * OCH + oc];
    bmix[i] = a;
}

// Block = (sample b = blk&63, 2-row tile). M=128 x N=112, 4 waves (32 oc each).
// K in 4 quarters (32 ch x 9 k-steps). Quarter slab staged with global_load_lds
// into a 20,480 B double buffer. stage(q+1) issues at top of compute(q) so the
// vmcnt drain at the end-of-quarter barrier is free. A streams from XCD-local
// L2 with a depth-2 register pipeline. (Exact R1 version — 62.4 us measured.)
__global__ __launch_bounds__(256, 4) void condconv_mfma(
        const unsigned short* __restrict__ xt, const unsigned short* __restrict__ wmix,
        const float* __restrict__ bmix, float* __restrict__ out) {
    __shared__ unsigned short patch[2][BUFE];   // 40,960 B

    int blk  = blockIdx.x;
    int b    = blk & 63;
    int tile = blk >> 6;               // 0..27
    int oh0  = tile * 2;
    int tid  = threadIdx.x;
    int wave = tid >> 6, lane = tid & 63, ln = lane & 15, quad = lane >> 4;

    // A: wmix[b][s][oc][32]; per-lane base for (oc = wave*32+ln, k-sub = quad*8)
    const unsigned short* ap = wmix + (size_t)b * WMIX_PS
                             + (size_t)(wave * 32 + ln) * 32 + quad * 8;

    const unsigned short* xbase = xt + (size_t)(b * 4) * PLANEE + (size_t)oh0 * ROWE;
    int g[5];
    #pragma unroll
    for (int i = 0; i < 5; ++i) {
        int gi = wave * 320 + i * 64 + lane;
        g[i] = (gi < SLAB_CHUNKS) ? gi : (SLAB_CHUNKS - 1);   // clamp overrun lanes
    }

    // B bases + output offsets: n = nt*16 + ln
    int cb[7], offn[7];
    #pragma unroll
    for (int nt = 0; nt < 7; ++nt) {
        int n   = nt * 16 + ln;
        int row = (n >= 56) ? 1 : 0;
        int ow  = n - row * 56;
        cb[nt]   = (row * 58 + ow) * CELLE + quad * 8;
        offn[nt] = (oh0 + row) * HW + ow;
    }

    f32x4 acc[2][7] = {};

    auto stage = [&](int q, int bf) {
        const unsigned short* sq = xbase + (size_t)q * PLANEE;
        unsigned short* l0 = &patch[bf][0] + wave * 2560;     // wave*320 chunks
        #pragma unroll
        for (int i = 0; i < 5; ++i)
            gl16(sq + (size_t)g[i] * 8, l0 + i * 512);
    };

    stage(0, 0);
    bf16x8 pa0[2], pa1[2];
    pa0[0] = *(const bf16x8*)(ap);
    pa1[0] = *(const bf16x8*)(ap + 512);
    pa0[1] = *(const bf16x8*)(ap + 4096);
    pa1[1] = *(const bf16x8*)(ap + 4096 + 512);
    __syncthreads();

    #pragma unroll
    for (int q = 0; q < 4; ++q) {
        if (q < 3) stage(q + 1, (q + 1) & 1);
        #pragma unroll
        for (int s9 = 0; s9 < 9; ++s9) {
            const int s = q * 9 + s9;
            bf16x8 ca0 = pa0[s & 1], ca1 = pa1[s & 1];
            const int sp = (s + 2 < NSTEP) ? (s + 2) : (NSTEP - 1);
            pa0[s & 1] = *(const bf16x8*)(ap + (size_t)sp * 4096);
            pa1[s & 1] = *(const bf16x8*)(ap + (size_t)sp * 4096 + 512);
            const int r = s9 / 3, sc = s9 - r * 3;
            const int pshift = (r * 58 + sc) * CELLE;
            #pragma unroll
            for (int nt = 0; nt < 7; ++nt) {
                bf16x8 bb = *(const bf16x8*)&patch[q & 1][cb[nt] + pshift];
                acc[0][nt] = __builtin_amdgcn_mfma_f32_16x16x32_bf16(ca0, bb, acc[0][nt], 0, 0, 0);
                acc[1][nt] = __builtin_amdgcn_mfma_f32_16x16x32_bf16(ca1, bb, acc[1][nt], 0, 0, 0);
            }
        }
        __syncthreads();
    }

    // epilogue: D layout col(lane&15)=pixel, row(quad*4+reg)=oc
    const float* bmb = bmix + b * OCH;
    float* ob = out + (size_t)b * OCH * HW * HW;
    #pragma unroll
    for (int mt = 0; mt < 2; ++mt) {
        #pragma unroll
        for (int rg = 0; rg < 4; ++rg) {
            int oc = wave * 32 + mt * 16 + quad * 4 + rg;
            float bv = bmb[oc];
            #pragma unroll
            for (int nt = 0; nt < 7; ++nt)
                ob[(size_t)oc * (HW * HW) + offn[nt]] = acc[mt][nt][rg] + bv;
        }
    }
}

extern "C" void kernel_launch(void* const* d_in, const int* in_sizes, int n_in,
                              void* d_out, int out_size, void* d_ws, size_t ws_size,
                              hipStream_t stream) {
    (void)in_sizes; (void)n_in; (void)out_size; (void)ws_size;
    const float* x    = (const float*)d_in[0];
    const float* rw   = (const float*)d_in[1];
    const float* wgt  = (const float*)d_in[2];
    const float* bias = (const float*)d_in[3];
    float* outp = (float*)d_out;

    // ws layout: wmix (18,874,368 B) | bmix (32 KB) | x_t (68,894,720 B)
    unsigned short* wmix = (unsigned short*)d_ws;
    float* bmix = (float*)((char*)d_ws + (size_t)BS * WMIX_PS * 2);
    unsigned short* xtw = (unsigned short*)((char*)d_ws + (size_t)BS * WMIX_PS * 2 + 32768);

    hipLaunchKernelGGL(prep_xt,   dim3(BS, 58), dim3(256), 0, stream, x, xtw);
    hipLaunchKernelGGL(prep_wmix, dim3(OCH, 4), dim3(256), 0, stream, rw, wgt, wmix);
    hipLaunchKernelGGL(prep_bmix, dim3(32),     dim3(256), 0, stream, rw, bias, bmix);
    hipLaunchKernelGGL(condconv_mfma, dim3(BS * 28), dim3(256), 0, stream,
                       xtw, wmix, bmix, outp);
}

// Round 6
// 268.188 us; speedup vs baseline: 1.0854x; 1.0116x over previous
//
#include <hip/hip_runtime.h>

#define BS    64
#define CIN   128
#define OCH   128
#define HW    56
#define KEXP  8
#define KTOT  1152             // 9 * 128
#define NSTEP 36               // k-steps of 32
#define PLANEC 3364            // 58*58 16B-chunks per (b,quarter,octet) plane
#define WMIX_PS (NSTEP * OCH * 32)   // 147456 elems per sample
#define TPAD  58               // prep_xt LDS row stride (conflict-free gather)

typedef __bf16 bf16x8 __attribute__((ext_vector_type(8)));
typedef float  f32x4  __attribute__((ext_vector_type(4)));

__device__ __forceinline__ unsigned f2bf(float f) {
    union { float f; unsigned u; } v; v.f = f;
    unsigned r = v.u + 0x7fffu + ((v.u >> 16) & 1u);   // RNE
    return r >> 16;
}

__device__ __forceinline__ void gl16(const unsigned short* g, unsigned short* l) {
    __builtin_amdgcn_global_load_lds(
        (const __attribute__((address_space(1))) void*)g,
        (__attribute__((address_space(3))) void*)l, 16, 0, 0);
}

// x [64][128][56][56] f32 -> x_t [64][qq=4][oct=4][58][58] chunks of 16 B
// (chunk = 8 channels c = qq*32+oct*8+k, bf16, zero halos).
// Block = (b, padded row ihp). Phase 1: float4 loads -> LDS [c][TPAD].
// Phase 2: 8-channel gather per chunk (stride-58 rows, conflict-free),
// coalesced uint4 stores.
__global__ __launch_bounds__(256) void prep_xt(const float* __restrict__ x,
                                               unsigned short* __restrict__ xt) {
    __shared__ unsigned short t[CIN * TPAD];   // 14,848 B
    int b = blockIdx.x, ihp = blockIdx.y;      // ihp in [0,58)
    int tid = threadIdx.x;
    bool border = (ihp == 0) || (ihp == 57);
    if (!border) {
        int ih = ihp - 1;
        const float* xr = x + (size_t)b * CIN * HW * HW + (size_t)ih * HW;
        #pragma unroll
        for (int i7 = 0; i7 < 7; ++i7) {               // 1792 float4 = 7/thread
            int i = i7 * 256 + tid;
            int c = i / 14, w4 = i - c * 14;
            float4 v = *(const float4*)(xr + (size_t)c * (HW * HW) + w4 * 4);
            unsigned lo = f2bf(v.x) | (f2bf(v.y) << 16);
            unsigned hi = f2bf(v.z) | (f2bf(v.w) << 16);
            *(unsigned*)&t[c * TPAD + w4 * 4]     = lo;
            *(unsigned*)&t[c * TPAD + w4 * 4 + 2] = hi;
        }
    }
    __syncthreads();
    for (int j = tid; j < 928; j += 256) {             // 4*4*58 chunks
        int qq = j / 232, rr = j - qq * 232;
        int oct = rr / 58, col = rr - oct * 58;
        union { unsigned short u[8]; uint4 v; } o;
        o.v = make_uint4(0u, 0u, 0u, 0u);
        if (!border && col >= 1 && col <= 56) {
            #pragma unroll
            for (int k = 0; k < 8; ++k)
                o.u[k] = t[(qq * 32 + oct * 8 + k) * TPAD + (col - 1)];
        }
        *(uint4*)&xt[(((size_t)(b * 16 + qq * 4 + oct)) * PLANEC
                      + (size_t)ihp * 58 + col) * 8] = o.v;
    }
}

// Block = (oc, b-group of 16). wmix layout: [b][s=0..35][oc][32] bf16,
// s = q*9 + rs, chunk = channels q*32..q*32+31 of tap rs.  (unchanged)
__global__ __launch_bounds__(256) void prep_wmix(
        const float* __restrict__ rw, const float* __restrict__ wgt,
        unsigned short* __restrict__ wmix) {
    __shared__ float wlds[KEXP * KTOT];     // 36.9 KB
    __shared__ float rwl[16 * KEXP];
    int oc  = blockIdx.x;
    int bg  = blockIdx.y;
    int tid = threadIdx.x;

    if (tid < 16 * KEXP) rwl[tid] = rw[bg * 16 * KEXP + tid];
    const float* wsrc = wgt + (size_t)oc * KTOT;
    #pragma unroll
    for (int e = 0; e < KEXP; ++e) {
        const float* we = wsrc + (size_t)e * OCH * KTOT;
        for (int j = tid; j < KTOT; j += 256) wlds[e * KTOT + j] = we[j];
    }
    __syncthreads();

    for (int t = tid; t < KTOT; t += 256) {
        int c = t & 127, rs = t >> 7;
        int q = c >> 5, cl = c & 31;
        size_t oidx = ((size_t)(q * 9 + rs) * OCH + oc) * 32 + cl;
        float w8[KEXP];
        #pragma unroll
        for (int e = 0; e < KEXP; ++e) w8[e] = wlds[e * KTOT + c * 9 + rs];
        #pragma unroll
        for (int b = 0; b < 16; ++b) {
            float a = 0.f;
            #pragma unroll
            for (int e = 0; e < KEXP; ++e) a += rwl[b * KEXP + e] * w8[e];
            wmix[(size_t)(bg * 16 + b) * WMIX_PS + oidx] = (unsigned short)f2bf(a);
        }
    }
}

__global__ __launch_bounds__(256) void prep_bmix(
        const float* __restrict__ rw, const float* __restrict__ bias,
        float* __restrict__ bmix) {
    int i = blockIdx.x * 256 + threadIdx.x;
    int b = i >> 7, oc = i & 127;
    float a = 0.f;
    #pragma unroll
    for (int e = 0; e < KEXP; ++e) a += rw[b * KEXP + e] * bias[e * OCH + oc];
    bmix[i] = a;
}

// R3-proven skeleton: block = (sample b = blk&63, 2-row tile), 256 threads =
// 4 waves, wave owns 32 oc (2 m-subtiles), acc[2][7], depth-2 A pipeline,
// double-buffered staging. ONLY the addressing is new: chunked x_t layout ->
// staging is 4 linear gl16 per wave (wave = its octet section), and B-reads
// are aligned ds_read_b128 at chunk (quad*256 + row*58 + col) -> 16
// consecutive lanes read contiguous chunks => zero bank conflicts.
__global__ __launch_bounds__(256, 4) void condconv_mfma(
        const unsigned short* __restrict__ xt, const unsigned short* __restrict__ wmix,
        const float* __restrict__ bmix, float* __restrict__ out) {
    __shared__ unsigned short patch[2][8192];   // 2 x 16,384 B

    int blk  = blockIdx.x;
    int b    = blk & 63;
    int tile = blk >> 6;               // 0..27
    int oh0  = tile * 2;
    int tid  = threadIdx.x;
    int wave = tid >> 6, lane = tid & 63, ln = lane & 15, quad = lane >> 4;

    // A: wmix[b][s][oc][32]; per-lane base (oc = wave*32 + ln, k-oct = quad)
    const unsigned short* ap = wmix + (size_t)b * WMIX_PS
                             + (size_t)(wave * 32 + ln) * 32 + quad * 8;

    const unsigned short* xb = xt + (size_t)(b * 16) * (PLANEC * 8)
                             + (size_t)oh0 * 58 * 8;

    // staging: wave w stages octet w; 4 gl16 of 64 chunks, clamp tail
    int rcl[4];
    #pragma unroll
    for (int i = 0; i < 4; ++i) {
        int rc = i * 64 + lane;
        rcl[i] = (rc > 231) ? 231 : rc;          // clamp into valid 232-chunk slab
    }

    // B bases + output offsets: n = nt*16 + ln  (N=112 exact)
    int cb[7], offn[7];
    #pragma unroll
    for (int nt = 0; nt < 7; ++nt) {
        int n   = nt * 16 + ln;
        int row = (n >= 56) ? 1 : 0;
        int ow  = n - row * 56;
        cb[nt]   = (quad * 256 + row * 58 + ow) * 8;   // ushort index
        offn[nt] = (oh0 + row) * HW + ow;
    }

    f32x4 acc[2][7] = {};

    auto stage = [&](int qq, int bf) {
        const unsigned short* sq = xb + (size_t)(qq * 4 + wave) * (PLANEC * 8);
        #pragma unroll
        for (int i = 0; i < 4; ++i)
            gl16(sq + (size_t)rcl[i] * 8, &patch[bf][(wave * 256 + i * 64) * 8]);
    };

    stage(0, 0);
    bf16x8 pa0[2], pa1[2];
    pa0[0] = *(const bf16x8*)(ap);
    pa1[0] = *(const bf16x8*)(ap + 512);
    pa0[1] = *(const bf16x8*)(ap + 4096);
    pa1[1] = *(const bf16x8*)(ap + 4096 + 512);
    __syncthreads();

    #pragma unroll
    for (int qq = 0; qq < 4; ++qq) {
        if (qq < 3) stage(qq + 1, (qq + 1) & 1);
        #pragma unroll
        for (int s9 = 0; s9 < 9; ++s9) {
            const int s = qq * 9 + s9;
            bf16x8 ca0 = pa0[s & 1], ca1 = pa1[s & 1];
            const int sp = (s + 2 < NSTEP) ? (s + 2) : (NSTEP - 1);
            pa0[s & 1] = *(const bf16x8*)(ap + (size_t)sp * 4096);
            pa1[s & 1] = *(const bf16x8*)(ap + (size_t)sp * 4096 + 512);
            const int r = s9 / 3, sc = s9 - r * 3;
            const int pshift = (r * 58 + sc) * 8;
            #pragma unroll
            for (int nt = 0; nt < 7; ++nt) {
                bf16x8 bb = *(const bf16x8*)&patch[qq & 1][cb[nt] + pshift];
                acc[0][nt] = __builtin_amdgcn_mfma_f32_16x16x32_bf16(ca0, bb, acc[0][nt], 0, 0, 0);
                acc[1][nt] = __builtin_amdgcn_mfma_f32_16x16x32_bf16(ca1, bb, acc[1][nt], 0, 0, 0);
            }
        }
        __syncthreads();
    }

    // epilogue: D layout col(lane&15)=pixel, row(quad*4+reg)=oc
    const float* bmb = bmix + b * OCH;
    float* ob = out + (size_t)b * OCH * HW * HW;
    #pragma unroll
    for (int mt = 0; mt < 2; ++mt) {
        #pragma unroll
        for (int rg = 0; rg < 4; ++rg) {
            int oc = wave * 32 + mt * 16 + quad * 4 + rg;
            float bv = bmb[oc];
            #pragma unroll
            for (int nt = 0; nt < 7; ++nt)
                ob[(size_t)oc * (HW * HW) + offn[nt]] = acc[mt][nt][rg] + bv;
        }
    }
}

extern "C" void kernel_launch(void* const* d_in, const int* in_sizes, int n_in,
                              void* d_out, int out_size, void* d_ws, size_t ws_size,
                              hipStream_t stream) {
    (void)in_sizes; (void)n_in; (void)out_size; (void)ws_size;
    const float* x    = (const float*)d_in[0];
    const float* rw   = (const float*)d_in[1];
    const float* wgt  = (const float*)d_in[2];
    const float* bias = (const float*)d_in[3];
    float* outp = (float*)d_out;

    // ws layout: wmix (18,874,368 B) | bmix (32 KB) | x_t (55,115,776 B)
    unsigned short* wmix = (unsigned short*)d_ws;
    float* bmix = (float*)((char*)d_ws + (size_t)BS * WMIX_PS * 2);
    unsigned short* xtw = (unsigned short*)((char*)d_ws + (size_t)BS * WMIX_PS * 2 + 32768);

    hipLaunchKernelGGL(prep_xt,   dim3(BS, 58), dim3(256), 0, stream, x, xtw);
    hipLaunchKernelGGL(prep_wmix, dim3(OCH, 4), dim3(256), 0, stream, rw, wgt, wmix);
    hipLaunchKernelGGL(prep_bmix, dim3(32),     dim3(256), 0, stream, rw, bias, bmix);
    hipLaunchKernelGGL(condconv_mfma, dim3(BS * 28), dim3(256), 0, stream,
                       xtw, wmix, bmix, outp);
}